// Round 3
// baseline (2724.358 us; speedup 1.0000x reference)
//
#include <hip/hip_runtime.h>

// Problem constants (from reference setup_inputs)
#define B_DIM 16
#define D_DIM 768
#define T_DIM 4096
#define K_DIM 1024

#define MT 128   // t-rows per block
#define KT 128   // k-tile
#define DB 16    // d-slice staged in LDS

// d values live near 768 -> binade [512,1024), fp32 ulp = 2^-14
#define GRID_ULP 6.103515625e-05f
#define MARGIN   (3.0f * GRID_ULP)

// out layout (all float32):
// out[0]                         = commitment loss
// out[1 + (b*D + d)*T + t]       = z_q_st (== z_q forward)
// out[1 + B*D*T + b*T + t]       = idx (as float, exactly representable)
#define IDX_OFF (1 + (size_t)B_DIM * D_DIM * T_DIM)

// ---------------- prep: ||e_k||^2 (fp64 -> fp32) into ws; zero loss ----------------
__global__ __launch_bounds__(64) void vq_prep(const float* __restrict__ e,
                                              float* __restrict__ wsE,
                                              float* __restrict__ out)
{
    if (blockIdx.x == 0 && threadIdx.x == 0) out[0] = 0.0f;
    int k = blockIdx.x * 64 + threadIdx.x;
    if (k < K_DIM) {
        const float* er = e + (size_t)k * D_DIM;
        double s = 0.0;
        for (int d = 0; d < D_DIM; ++d) {
            double ed = (double)er[d];
            s = fma(ed, ed, s);
        }
        wsE[k] = (float)s;
    }
}

// ---------------- main distance pass: fp32 scores, top-2 tracking + flagging ----------------
__global__ __launch_bounds__(256) void vq_main(const float* __restrict__ z,
                                               const float* __restrict__ e,
                                               const float* __restrict__ wsE,
                                               float* __restrict__ out)
{
    __shared__ float z_lds[DB][132];
    __shared__ float e_lds[DB][132];
    __shared__ float ee_lds[K_DIM];

    const int tid  = threadIdx.x;
    const int mIdx = blockIdx.x;           // 512 blocks = 16 b * 32 t-tiles
    const int b    = mIdx >> 5;
    const int t0   = (mIdx & 31) * MT;
    const float* zb = z + (size_t)b * D_DIM * T_DIM;

    #pragma unroll
    for (int j = 0; j < 4; ++j) ee_lds[tid + j * 256] = wsE[tid + j * 256];

    const int tx = tid & 15;   // k-subtile owner (8 k's)
    const int ty = tid >> 4;   // t-subtile owner (8 t's)

    float bv[8], sv[8];
    int   bk[8], sk[8];
    #pragma unroll
    for (int i = 0; i < 8; ++i) {
        bv[i] = 3.4e38f; bk[i] = 0x7fffffff;
        sv[i] = 3.4e38f; sk[i] = 0x7fffffff;
    }

    for (int k0 = 0; k0 < K_DIM; k0 += KT) {
        float acc[8][8];
        #pragma unroll
        for (int i = 0; i < 8; ++i)
            #pragma unroll
            for (int j = 0; j < 8; ++j) acc[i][j] = 0.0f;

        for (int d0 = 0; d0 < D_DIM; d0 += DB) {
            __syncthreads();   // protect LDS from previous compute readers
            {   // stage z-slice: [DB][128], coalesced over t
                int dd = tid >> 4;
                int toff = (tid & 15) * 8;
                const float* src = zb + (size_t)(d0 + dd) * T_DIM + t0 + toff;
                float4 a  = *reinterpret_cast<const float4*>(src);
                float4 b4 = *reinterpret_cast<const float4*>(src + 4);
                *reinterpret_cast<float4*>(&z_lds[dd][toff])     = a;
                *reinterpret_cast<float4*>(&z_lds[dd][toff + 4]) = b4;
            }
            {   // stage e-slice transposed: e[k0+kk][d0..d0+15] -> e_lds[d][kk]
                int kk = tid >> 1;
                int h  = tid & 1;
                const float* src = e + (size_t)(k0 + kk) * D_DIM + d0 + h * 8;
                float4 a  = *reinterpret_cast<const float4*>(src);
                float4 b4 = *reinterpret_cast<const float4*>(src + 4);
                e_lds[h * 8 + 0][kk] = a.x;
                e_lds[h * 8 + 1][kk] = a.y;
                e_lds[h * 8 + 2][kk] = a.z;
                e_lds[h * 8 + 3][kk] = a.w;
                e_lds[h * 8 + 4][kk] = b4.x;
                e_lds[h * 8 + 5][kk] = b4.y;
                e_lds[h * 8 + 6][kk] = b4.z;
                e_lds[h * 8 + 7][kk] = b4.w;
            }
            __syncthreads();

            #pragma unroll
            for (int dd = 0; dd < DB; ++dd) {
                float z8[8], e8[8];
                *reinterpret_cast<float4*>(z8)     = *reinterpret_cast<const float4*>(&z_lds[dd][ty * 8]);
                *reinterpret_cast<float4*>(z8 + 4) = *reinterpret_cast<const float4*>(&z_lds[dd][ty * 8 + 4]);
                *reinterpret_cast<float4*>(e8)     = *reinterpret_cast<const float4*>(&e_lds[dd][tx * 8]);
                *reinterpret_cast<float4*>(e8 + 4) = *reinterpret_cast<const float4*>(&e_lds[dd][tx * 8 + 4]);
                #pragma unroll
                for (int i = 0; i < 8; ++i)
                    #pragma unroll
                    for (int j = 0; j < 8; ++j)
                        acc[i][j] = fmaf(z8[i], e8[j], acc[i][j]);
            }
        }

        // fold this k-tile into running top-2 (lexicographic (value, k))
        #pragma unroll
        for (int i = 0; i < 8; ++i) {
            #pragma unroll
            for (int j = 0; j < 8; ++j) {
                int k = k0 + tx * 8 + j;
                float sc = ee_lds[k] - 2.0f * acc[i][j];
                if (sc < bv[i] || (sc == bv[i] && k < bk[i])) {
                    sv[i] = bv[i]; sk[i] = bk[i];
                    bv[i] = sc;    bk[i] = k;
                } else if (sc < sv[i] || (sc == sv[i] && k < sk[i])) {
                    sv[i] = sc;    sk[i] = k;
                }
            }
        }
    }

    // cross-thread top-2 merge via 16-lane butterfly
    #pragma unroll
    for (int m = 1; m < 16; m <<= 1) {
        #pragma unroll
        for (int i = 0; i < 8; ++i) {
            float ov  = __shfl_xor(bv[i], m);
            int   ok  = __shfl_xor(bk[i], m);
            float osv = __shfl_xor(sv[i], m);
            int   osk = __shfl_xor(sk[i], m);
            if (ov < bv[i] || (ov == bv[i] && ok < bk[i])) {
                if (bv[i] < osv || (bv[i] == osv && bk[i] < osk)) { sv[i] = bv[i]; sk[i] = bk[i]; }
                else                                              { sv[i] = osv;  sk[i] = osk;  }
                bv[i] = ov; bk[i] = ok;
            } else {
                if (ov < sv[i] || (ov == sv[i] && ok < sk[i])) { sv[i] = ov; sk[i] = ok; }
            }
        }
    }

    if (tx == 0) {
        #pragma unroll
        for (int i = 0; i < 8; ++i) {
            int gt = t0 + ty * 8 + i;
            float enc = (sv[i] - bv[i] < MARGIN) ? (-1.0f - (float)bk[i]) : (float)bk[i];
            out[IDX_OFF + (size_t)b * T_DIM + gt] = enc;
        }
    }
}

// ---------------- fixup: emulate numpy fp32 d = fl(fl(A+E_k) - 2*M_k) over ALL k ----------------
// M_k emulated as OpenBLAS-style sequential fp32 fmaf chain in d-order, split in two
// 384-panels (GEMM_Q=384): M = fl(chain(0..383) + chain(384..767)).
__global__ __launch_bounds__(64) void vq_fixup(const float* __restrict__ z,
                                               const float* __restrict__ e,
                                               const float* __restrict__ wsE,
                                               float* __restrict__ out)
{
    __shared__ float zrow[D_DIM];
    const int lane = threadIdx.x;
    const int base = blockIdx.x * 64;

    for (int r = 0; r < 64; ++r) {
        int row = base + r;
        float v = out[IDX_OFF + row];      // wave-uniform
        if (v >= 0.0f) continue;
        int b = row >> 12;                 // T = 4096
        int t = row & 4095;
        const float* zp = z + (size_t)b * D_DIM * T_DIM + t;

        __syncthreads();
        for (int d = lane; d < D_DIM; d += 64) zrow[d] = zp[(size_t)d * T_DIM];
        __syncthreads();

        // A = fl32(fp64 sum z^2)  (ordering invariant to exact-grid shifts of A)
        double a64 = 0.0;
        for (int d = lane; d < D_DIM; d += 64) {
            double zd = (double)zrow[d];
            a64 = fma(zd, zd, a64);
        }
        #pragma unroll
        for (int m = 1; m < 64; m <<= 1) a64 += __shfl_xor(a64, m);
        const float Af = (float)a64;

        // per-lane scan: k = lane + 64*j, ascending; 4 interleaved chains for ILP
        float bd = 3.4e38f;
        int   bkk = 0x7fffffff;
        for (int jg = 0; jg < 16; jg += 4) {
            const float* ep[4];
            int kk[4];
            #pragma unroll
            for (int q = 0; q < 4; ++q) {
                kk[q] = lane + (jg + q) * 64;
                ep[q] = e + (size_t)kk[q] * D_DIM;
            }
            float ca[4] = {0.f, 0.f, 0.f, 0.f};
            for (int d = 0; d < 384; d += 4) {
                float4 zv = *reinterpret_cast<const float4*>(&zrow[d]);
                #pragma unroll
                for (int q = 0; q < 4; ++q) {
                    float4 ev = *reinterpret_cast<const float4*>(ep[q] + d);
                    ca[q] = fmaf(zv.x, ev.x, ca[q]);
                    ca[q] = fmaf(zv.y, ev.y, ca[q]);
                    ca[q] = fmaf(zv.z, ev.z, ca[q]);
                    ca[q] = fmaf(zv.w, ev.w, ca[q]);
                }
            }
            float cb[4] = {0.f, 0.f, 0.f, 0.f};
            for (int d = 384; d < 768; d += 4) {
                float4 zv = *reinterpret_cast<const float4*>(&zrow[d]);
                #pragma unroll
                for (int q = 0; q < 4; ++q) {
                    float4 ev = *reinterpret_cast<const float4*>(ep[q] + d);
                    cb[q] = fmaf(zv.x, ev.x, cb[q]);
                    cb[q] = fmaf(zv.y, ev.y, cb[q]);
                    cb[q] = fmaf(zv.z, ev.z, cb[q]);
                    cb[q] = fmaf(zv.w, ev.w, cb[q]);
                }
            }
            #pragma unroll
            for (int q = 0; q < 4; ++q) {
                float M  = ca[q] + cb[q];          // fl(S1+S2)
                float t1 = Af + wsE[kk[q]];        // fl(A+E_k)
                float dq = t1 - 2.0f * M;          // fl(fl(A+E_k) - 2M)
                if (dq < bd || (dq == bd && kk[q] < bkk)) { bd = dq; bkk = kk[q]; }
            }
        }

        // cross-lane lex-min -> numpy first-occurrence argmin
        #pragma unroll
        for (int m = 1; m < 64; m <<= 1) {
            float od = __shfl_xor(bd, m);
            int   ok = __shfl_xor(bkk, m);
            if (od < bd || (od == bd && ok < bkk)) { bd = od; bkk = ok; }
        }
        if (lane == 0) out[IDX_OFF + row] = (float)bkk;
    }
}

// ---------------- gather z_q, transposed write, fused loss ----------------
__global__ __launch_bounds__(256) void vq_out(const float* __restrict__ z,
                                              const float* __restrict__ e,
                                              float* __restrict__ out)
{
    __shared__ float lred[4];
    const int tid  = threadIdx.x;
    const int mIdx = blockIdx.x;
    const int b    = mIdx >> 5;
    const int t0   = (mIdx & 31) * MT;

    const int t  = tid & 127;
    const int ds = tid >> 7;
    const int gt = t0 + t;
    const int k  = (int)out[IDX_OFF + (size_t)b * T_DIM + gt];
    const float* er = e + (size_t)k * D_DIM;
    float lsum = 0.0f;
    for (int d0 = ds * 4; d0 < D_DIM; d0 += 8) {
        float4 v = *reinterpret_cast<const float4*>(er + d0);
        float vv[4];
        *reinterpret_cast<float4*>(vv) = v;
        #pragma unroll
        for (int j = 0; j < 4; ++j) {
            size_t o = (size_t)(b * D_DIM + d0 + j) * T_DIM + gt;
            float zv = z[o];
            out[1 + o] = vv[j];
            float diff = zv - vv[j];
            lsum = fmaf(diff, diff, lsum);
        }
    }
    #pragma unroll
    for (int off = 32; off > 0; off >>= 1) lsum += __shfl_down(lsum, off);
    if ((tid & 63) == 0) lred[tid >> 6] = lsum;
    __syncthreads();
    if (tid == 0) {
        float tot = lred[0] + lred[1] + lred[2] + lred[3];
        atomicAdd(out, tot * (1.0f / ((float)B_DIM * D_DIM * T_DIM)));
    }
}

extern "C" void kernel_launch(void* const* d_in, const int* in_sizes, int n_in,
                              void* d_out, int out_size, void* d_ws, size_t ws_size,
                              hipStream_t stream) {
    const float* z = (const float*)d_in[0];
    const float* e = (const float*)d_in[1];
    float* out = (float*)d_out;
    float* wsE = (float*)d_ws;
    (void)in_sizes; (void)n_in; (void)out_size; (void)ws_size;

    vq_prep<<<dim3(16), dim3(64), 0, stream>>>(e, wsE, out);
    vq_main<<<dim3((B_DIM * T_DIM) / MT), dim3(256), 0, stream>>>(z, e, wsE, out);
    vq_fixup<<<dim3((B_DIM * T_DIM) / 64), dim3(64), 0, stream>>>(z, e, wsE, out);
    vq_out<<<dim3((B_DIM * T_DIM) / MT), dim3(256), 0, stream>>>(z, e, out);
}

// Round 5
// 1144.672 us; speedup vs baseline: 2.3800x; 2.3800x over previous
//
#include <hip/hip_runtime.h>

typedef unsigned short u16;
typedef unsigned int   u32;

#define B_DIM 16
#define D_DIM 768
#define T_DIM 4096
#define K_DIM 1024
#define NROW  (B_DIM * T_DIM)   // 65536 rows (b*T + t)

// out layout (float32): out[0]=loss; out[1 + (b*D+d)*T + t]=z_q_st; out[IDX_OFF + b*T + t]=idx
#define IDX_OFF (1 + (size_t)B_DIM * D_DIM * T_DIM)

// stage-1 flag margin: 2*G (numpy double-quantization slack, G=2^-14) + ~12 sigma of bf16-z score error
#define MARGIN 7.0e-4f

// ---- scratch carved out of d_out's z_q region (overwritten by vq_out at the end) ----
#define ZH_OFF   ((size_t)64)                                   // bf16 z, [row][768], pre-swizzled
#define EH_OFF   (ZH_OFF + (size_t)NROW * D_DIM * 2)            // bf16 e hi, [k][768], pre-swizzled
#define EL_OFF   (EH_OFF + (size_t)K_DIM * D_DIM * 2)           // bf16 e lo
#define EE_OFF   (EL_OFF + (size_t)K_DIM * D_DIM * 2)           // fp32 ||e_k||^2
#define CNT_OFF  (EE_OFF + (size_t)K_DIM * 4)                   // int flag counter
#define LIST_OFF (CNT_OFF + 64)                                 // int flagged-row list (<=65536)

static __device__ inline u16 f2bf(float x) {
    u32 u = __float_as_uint(x);
    u += 0x7fffu + ((u >> 16) & 1u);
    return (u16)(u >> 16);
}
static __device__ inline float bf2f(u16 h) { return __uint_as_float(((u32)h) << 16); }

typedef __attribute__((ext_vector_type(8))) short short8v;
typedef __attribute__((ext_vector_type(4))) float float4v;

static __device__ inline void gload16(const u16* g, u16* l) {
    __builtin_amdgcn_global_load_lds(
        (const __attribute__((address_space(1))) u32*)g,
        (__attribute__((address_space(3))) u32*)(uintptr_t)(void*)l,
        16, 0, 0);
}

// ---------------- prep: e split (hi/lo bf16, pre-swizzled) + ||e||^2 + zero cnt/loss ----------------
__global__ __launch_bounds__(64) void vq_prep_e(const float* __restrict__ e,
                                                u16* __restrict__ eh, u16* __restrict__ el,
                                                float* __restrict__ ee, int* __restrict__ cnt,
                                                float* __restrict__ out)
{
    int k = blockIdx.x * 64 + threadIdx.x;
    if (k == 0) { cnt[0] = 0; out[0] = 0.0f; }
    const float* er = e + (size_t)k * D_DIM;
    double s = 0.0;
    for (int d = 0; d < D_DIM; ++d) { double ed = (double)er[d]; s = fma(ed, ed, s); }
    ee[k] = (float)s;
    int kx = k & 7;
    for (int d = 0; d < D_DIM; ++d) {
        float x = er[d];
        u16 h = f2bf(x);
        u16 lo = f2bf(x - bf2f(h));
        int dst = (d >> 6) * 64 + ((((d >> 3) & 7) ^ kx) << 3) + (d & 7);
        eh[(size_t)k * D_DIM + dst] = h;
        el[(size_t)k * D_DIM + dst] = lo;
    }
}

// ---------------- prep: z transpose [b][d][t] -> bf16 zh[(b,t)][d], pre-swizzled ----------------
__global__ __launch_bounds__(256) void vq_prep_z(const float* __restrict__ z, u16* __restrict__ zh)
{
    __shared__ u16 tmp[64][72];
    int bi = blockIdx.x;
    int dg = bi % 12;
    int tg = (bi / 12) % 64;
    int b  = bi / (12 * 64);
    int tid = threadIdx.x;
    int tl4 = (tid & 15) * 4;
    int dl  = tid >> 4;
    #pragma unroll
    for (int p = 0; p < 4; ++p) {
        int d = dg * 64 + p * 16 + dl;
        const float* src = z + ((size_t)b * D_DIM + d) * T_DIM + tg * 64 + tl4;
        float4 v = *(const float4*)src;
        tmp[tl4 + 0][p * 16 + dl] = f2bf(v.x);
        tmp[tl4 + 1][p * 16 + dl] = f2bf(v.y);
        tmp[tl4 + 2][p * 16 + dl] = f2bf(v.z);
        tmp[tl4 + 3][p * 16 + dl] = f2bf(v.w);
    }
    __syncthreads();
    #pragma unroll
    for (int w = 0; w < 2; ++w) {
        int lin = tid * 2 + w;            // 0..511 = 64 rows x 8 chunks
        int tl  = lin >> 3;
        int c   = lin & 7;
        size_t row_g = (size_t)b * T_DIM + tg * 64 + tl;
        int cs = c ^ ((int)row_g & 7);
        uint4 val = *(const uint4*)&tmp[tl][c * 8];
        *(uint4*)(zh + row_g * D_DIM + dg * 64 + cs * 8) = val;
    }
}

// ---------------- main: bf16 MFMA scores, top-2 + flagging ----------------
__global__ __launch_bounds__(256, 2) void vq_main_mfma(const u16* __restrict__ zh,
                                                       const u16* __restrict__ eh,
                                                       const u16* __restrict__ el,
                                                       const float* __restrict__ ee_g,
                                                       float* __restrict__ out,
                                                       int* __restrict__ cnt,
                                                       int* __restrict__ list)
{
    __shared__ u16 zt[128 * 64];
    __shared__ u16 eht[128 * 64];
    __shared__ u16 elt[128 * 64];
    __shared__ float eeL[K_DIM];
    __shared__ float mv[128][2], msv[128][2];
    __shared__ int   mk[128][2], msk[128][2];

    const int tid  = threadIdx.x;
    const int wid  = tid >> 6;
    const int lane = tid & 63;
    const int wm = wid >> 1, wn = wid & 1;
    const int l15 = lane & 15, l4 = lane >> 4;
    const int row_block = blockIdx.x * 128;

    for (int i = tid; i < K_DIM; i += 256) eeL[i] = ee_g[i];

    float bv[16], sv[16];
    int   bk[16], sk[16];
    #pragma unroll
    for (int i = 0; i < 16; ++i) { bv[i] = 3.4e38f; bk[i] = 0x7fffffff; sv[i] = 3.4e38f; sk[i] = 0x7fffffff; }

    const int r8 = lane >> 3;
    const int ch = lane & 7;

    for (int n0 = 0; n0 < 8; ++n0) {
        float4v acc[4][4];
        #pragma unroll
        for (int mf = 0; mf < 4; ++mf)
            #pragma unroll
            for (int nf = 0; nf < 4; ++nf) acc[mf][nf] = (float4v)0.0f;

        for (int d0i = 0; d0i < 12; ++d0i) {
            const int d0 = d0i * 64;
            __syncthreads();
            #pragma unroll
            for (int q = 0; q < 4; ++q) {
                int lr = wid * 32 + q * 8;
                gload16(zh + (size_t)(row_block + lr + r8) * D_DIM + d0 + ch * 8, &zt[lr * 64]);
            }
            #pragma unroll
            for (int q = 0; q < 4; ++q) {
                int lr = wid * 32 + q * 8;
                gload16(eh + (size_t)(n0 * 128 + lr + r8) * D_DIM + d0 + ch * 8, &eht[lr * 64]);
            }
            #pragma unroll
            for (int q = 0; q < 4; ++q) {
                int lr = wid * 32 + q * 8;
                gload16(el + (size_t)(n0 * 128 + lr + r8) * D_DIM + d0 + ch * 8, &elt[lr * 64]);
            }
            __syncthreads();

            #pragma unroll
            for (int s = 0; s < 2; ++s) {
                short8v a[4], bh4[4], bl4[4];
                #pragma unroll
                for (int mf = 0; mf < 4; ++mf) {
                    int r = wm * 64 + mf * 16 + l15;
                    int cs = (s * 4 + l4) ^ (r & 7);
                    a[mf] = *(const short8v*)&zt[r * 64 + cs * 8];
                }
                #pragma unroll
                for (int nf = 0; nf < 4; ++nf) {
                    int r = wn * 64 + nf * 16 + l15;
                    int cs = (s * 4 + l4) ^ (r & 7);
                    bh4[nf] = *(const short8v*)&eht[r * 64 + cs * 8];
                    bl4[nf] = *(const short8v*)&elt[r * 64 + cs * 8];
                }
                #pragma unroll
                for (int mf = 0; mf < 4; ++mf)
                    #pragma unroll
                    for (int nf = 0; nf < 4; ++nf) {
                        acc[mf][nf] = __builtin_amdgcn_mfma_f32_16x16x32_bf16(a[mf], bh4[nf], acc[mf][nf], 0, 0, 0);
                        acc[mf][nf] = __builtin_amdgcn_mfma_f32_16x16x32_bf16(a[mf], bl4[nf], acc[mf][nf], 0, 0, 0);
                    }
            }
        }

        // fold into per-lane top-2 (16 row-slots)
        #pragma unroll
        for (int nf = 0; nf < 4; ++nf) {
            int kg = n0 * 128 + wn * 64 + nf * 16 + l15;
            float eev = eeL[kg];
            #pragma unroll
            for (int mf = 0; mf < 4; ++mf)
                #pragma unroll
                for (int rr = 0; rr < 4; ++rr) {
                    float sc = fmaf(-2.0f, acc[mf][nf][rr], eev);
                    int slot = mf * 4 + rr;
                    if (sc < bv[slot] || (sc == bv[slot] && kg < bk[slot])) {
                        sv[slot] = bv[slot]; sk[slot] = bk[slot];
                        bv[slot] = sc;       bk[slot] = kg;
                    } else if (sc < sv[slot] || (sc == sv[slot] && kg < sk[slot])) {
                        sv[slot] = sc; sk[slot] = kg;
                    }
                }
        }
    }

    // merge across the 16 lanes sharing l4 (masks 1,2,4,8): per-row top-2 over this wave's 512 codes
    #pragma unroll
    for (int m = 1; m < 16; m <<= 1) {
        #pragma unroll
        for (int i = 0; i < 16; ++i) {
            float ov  = __shfl_xor(bv[i], m);
            int   ok  = __shfl_xor(bk[i], m);
            float osv = __shfl_xor(sv[i], m);
            int   osk = __shfl_xor(sk[i], m);
            if (ov < bv[i] || (ov == bv[i] && ok < bk[i])) {
                if (bv[i] < osv || (bv[i] == osv && bk[i] < osk)) { sv[i] = bv[i]; sk[i] = bk[i]; }
                else                                              { sv[i] = osv;  sk[i] = osk;  }
                bv[i] = ov; bk[i] = ok;
            } else {
                if (ov < sv[i] || (ov == sv[i] && ok < sk[i])) { sv[i] = ov; sk[i] = ok; }
            }
        }
    }

    // each wave (wm,wn) covered only codebook half wn -> publish per-row top-2 to LDS and merge halves
    if (l15 == 0) {
        #pragma unroll
        for (int mf = 0; mf < 4; ++mf)
            #pragma unroll
            for (int rr = 0; rr < 4; ++rr) {
                int slot = mf * 4 + rr;
                int rl = wm * 64 + mf * 16 + l4 * 4 + rr;   // 0..127
                mv[rl][wn]  = bv[slot]; mk[rl][wn]  = bk[slot];
                msv[rl][wn] = sv[slot]; msk[rl][wn] = sk[slot];
            }
    }
    __syncthreads();
    if (tid < 128) {
        float b0 = mv[tid][0], s0 = msv[tid][0];
        int   k0 = mk[tid][0], j0 = msk[tid][0];
        float b1 = mv[tid][1], s1 = msv[tid][1];
        int   k1 = mk[tid][1], j1 = msk[tid][1];
        float BV, SV; int BK;
        if (b0 < b1 || (b0 == b1 && k0 < k1)) {
            BV = b0; BK = k0;
            SV = (s0 < b1 || (s0 == b1 && j0 < k1)) ? s0 : b1;
        } else {
            BV = b1; BK = k1;
            SV = (s1 < b0 || (s1 == b0 && j1 < k0)) ? s1 : b0;
        }
        int row = row_block + tid;
        out[IDX_OFF + row] = (float)BK;
        if (SV - BV < MARGIN) {
            int p = atomicAdd(cnt, 1);
            list[p] = row;
        }
    }
}

// ---------------- fixup: exact numpy-fp32 emulation for flagged rows (8 rows share one e sweep) ----------------
__global__ __launch_bounds__(256) void vq_fixup(const float* __restrict__ z,
                                                const float* __restrict__ e,
                                                const float* __restrict__ ee,
                                                float* __restrict__ out,
                                                const int* __restrict__ list,
                                                const int* __restrict__ cnt)
{
    __shared__ float zr[8][768];
    __shared__ double afl[8];
    __shared__ float dvL[256];
    __shared__ int   dkL[256];
    __shared__ int   rowsL[8];

    const int tid = threadIdx.x;
    int total = cnt[0];
    if (total > NROW) total = NROW;
    int ngroups = (total + 7) >> 3;

    for (int g = blockIdx.x; g < ngroups; g += gridDim.x) {
        int nr = total - g * 8; if (nr > 8) nr = 8;
        __syncthreads();
        if (tid < 8) rowsL[tid] = list[g * 8 + ((tid < nr) ? tid : 0)];
        __syncthreads();
        for (int i = tid; i < nr * 768; i += 256) {
            int r = i / 768; int d = i - r * 768;
            int row = rowsL[r];
            int b = row >> 12, t = row & 4095;
            zr[r][d] = z[((size_t)b * D_DIM + d) * T_DIM + t];
        }
        __syncthreads();
        {   // A = fl32(fp64 sum z^2) per row (ordering invariant to grid-multiple shifts -> any assoc ok)
            int r = tid >> 5, sub = tid & 31;
            double s = 0.0;
            for (int d = sub; d < 768 && r < nr; d += 32) { double zd = (double)zr[r][d]; s = fma(zd, zd, s); }
            #pragma unroll
            for (int m = 1; m < 32; m <<= 1) s += __shfl_xor(s, m);
            if (sub == 0 && r < 8) afl[r] = s;
        }
        __syncthreads();
        float Af[8];
        #pragma unroll
        for (int r = 0; r < 8; ++r) Af[r] = (float)afl[r];

        float bd[8]; int bkk[8];
        #pragma unroll
        for (int r = 0; r < 8; ++r) { bd[r] = 3.4e38f; bkk[r] = 0x7fffffff; }

        for (int q = 0; q < 4; ++q) {
            int k = tid + q * 256;
            const float* ep = e + (size_t)k * D_DIM;
            float c1[8], c2[8];
            #pragma unroll
            for (int r = 0; r < 8; ++r) c1[r] = 0.0f;
            for (int d = 0; d < 384; d += 4) {
                float4 ev = *(const float4*)(ep + d);
                #pragma unroll
                for (int r = 0; r < 8; ++r) {
                    float4 zv = *(const float4*)&zr[r][d];
                    c1[r] = fmaf(zv.x, ev.x, c1[r]);
                    c1[r] = fmaf(zv.y, ev.y, c1[r]);
                    c1[r] = fmaf(zv.z, ev.z, c1[r]);
                    c1[r] = fmaf(zv.w, ev.w, c1[r]);
                }
            }
            #pragma unroll
            for (int r = 0; r < 8; ++r) c2[r] = 0.0f;
            for (int d = 384; d < 768; d += 4) {
                float4 ev = *(const float4*)(ep + d);
                #pragma unroll
                for (int r = 0; r < 8; ++r) {
                    float4 zv = *(const float4*)&zr[r][d];
                    c2[r] = fmaf(zv.x, ev.x, c2[r]);
                    c2[r] = fmaf(zv.y, ev.y, c2[r]);
                    c2[r] = fmaf(zv.z, ev.z, c2[r]);
                    c2[r] = fmaf(zv.w, ev.w, c2[r]);
                }
            }
            float Ek = ee[k];
            #pragma unroll
            for (int r = 0; r < 8; ++r) {
                float M  = c1[r] + c2[r];        // fl(S1+S2), OpenBLAS 384-panel split
                float t1 = Af[r] + Ek;           // fl(A+E)
                float dq = t1 - 2.0f * M;        // fl(fl(A+E) - 2M)
                if (dq < bd[r] || (dq == bd[r] && k < bkk[r])) { bd[r] = dq; bkk[r] = k; }
            }
        }
        for (int r = 0; r < 8; ++r) {
            if (r >= nr) break;
            dvL[tid] = bd[r]; dkL[tid] = bkk[r];
            __syncthreads();
            if (tid < 64) {
                float v = dvL[tid]; int kk = dkL[tid];
                #pragma unroll
                for (int i = 1; i < 4; ++i) {
                    float v2 = dvL[tid + 64 * i]; int k2 = dkL[tid + 64 * i];
                    if (v2 < v || (v2 == v && k2 < kk)) { v = v2; kk = k2; }
                }
                #pragma unroll
                for (int m = 1; m < 64; m <<= 1) {
                    float v2 = __shfl_xor(v, m); int k2 = __shfl_xor(kk, m);
                    if (v2 < v || (v2 == v && k2 < kk)) { v = v2; kk = k2; }
                }
                if (tid == 0) out[IDX_OFF + rowsL[r]] = (float)kk;
            }
            __syncthreads();
        }
    }
}

// ---------------- gather z_q, transposed write, fused loss ----------------
__global__ __launch_bounds__(256) void vq_out(const float* __restrict__ z,
                                              const float* __restrict__ e,
                                              float* __restrict__ out)
{
    __shared__ float lred[4];
    const int tid  = threadIdx.x;
    const int mIdx = blockIdx.x;
    const int b    = mIdx >> 5;
    const int t0   = (mIdx & 31) * 128;

    const int t  = tid & 127;
    const int ds = tid >> 7;
    const int gt = t0 + t;
    const int k  = (int)out[IDX_OFF + (size_t)b * T_DIM + gt];
    const float* er = e + (size_t)k * D_DIM;
    float lsum = 0.0f;
    for (int d0 = ds * 4; d0 < D_DIM; d0 += 8) {
        float4 v = *(const float4*)(er + d0);
        float vv[4];
        *(float4*)vv = v;
        #pragma unroll
        for (int j = 0; j < 4; ++j) {
            size_t o = (size_t)(b * D_DIM + d0 + j) * T_DIM + gt;
            float zv = z[o];
            out[1 + o] = vv[j];
            float diff = zv - vv[j];
            lsum = fmaf(diff, diff, lsum);
        }
    }
    #pragma unroll
    for (int off = 32; off > 0; off >>= 1) lsum += __shfl_down(lsum, off);
    if ((tid & 63) == 0) lred[tid >> 6] = lsum;
    __syncthreads();
    if (tid == 0) {
        float tot = lred[0] + lred[1] + lred[2] + lred[3];
        atomicAdd(out, tot * (1.0f / ((float)B_DIM * D_DIM * T_DIM)));
    }
}

extern "C" void kernel_launch(void* const* d_in, const int* in_sizes, int n_in,
                              void* d_out, int out_size, void* d_ws, size_t ws_size,
                              hipStream_t stream) {
    const float* z = (const float*)d_in[0];
    const float* e = (const float*)d_in[1];
    float* out = (float*)d_out;
    char* ob = (char*)d_out;
    u16*   zh   = (u16*)(ob + ZH_OFF);
    u16*   eh   = (u16*)(ob + EH_OFF);
    u16*   el   = (u16*)(ob + EL_OFF);
    float* eeg  = (float*)(ob + EE_OFF);
    int*   cntp = (int*)(ob + CNT_OFF);
    int*   listp= (int*)(ob + LIST_OFF);
    (void)in_sizes; (void)n_in; (void)out_size; (void)d_ws; (void)ws_size;

    vq_prep_e<<<dim3(16), dim3(64), 0, stream>>>(e, eh, el, eeg, cntp, out);
    vq_prep_z<<<dim3(16 * 12 * 64), dim3(256), 0, stream>>>(z, zh);
    vq_main_mfma<<<dim3(NROW / 128), dim3(256), 0, stream>>>(zh, eh, el, eeg, out, cntp, listp);
    vq_fixup<<<dim3(512), dim3(256), 0, stream>>>(z, e, eeg, out, listp, cntp);
    vq_out<<<dim3(512), dim3(256), 0, stream>>>(z, e, out);
}